// Round 1
// baseline (80.116 us; speedup 1.0000x reference)
//
#include <hip/hip_runtime.h>
#include <hip/hip_fp16.h>

#define NPTS   33
#define NLUT   35937        // 33^3
#define PLANE  1048576      // 1024*1024
#define SPLIT  32           // blocks per (b,c) pair
#define PPB    (PLANE / SPLIT)
#define THREADS 1024

__global__ __launch_bounds__(THREADS)
void lut3d_kernel(const float* __restrict__ img,
                  const float* __restrict__ LUT,
                  float* __restrict__ out)
{
    // packed half2 pairs: slut[h] = (LUT[h], LUT[h+1])  -> one aligned b32 read
    // fetches both x-corners of a cell.
    __shared__ unsigned int slut[NLUT];

    const int blk = blockIdx.x;
    const int bc  = blk / SPLIT;      // 0..23  (b*3 + c)
    const int s   = blk % SPLIT;
    const int b   = bc / 3;
    const int c   = bc % 3;

    // ---- stage LUT[b][c] into LDS as packed fp16 pairs ----
    const float* lutg = LUT + (size_t)bc * NLUT;
    for (int h = threadIdx.x; h < NLUT; h += THREADS) {
        float v0 = lutg[h];
        float v1 = (h + 1 < NLUT) ? lutg[h + 1] : v0;
        __half2 p = __floats2half2_rn(v0, v1);
        slut[h] = *reinterpret_cast<unsigned int*>(&p);
    }
    __syncthreads();

    const float* px = img + ((size_t)b * 3 + 0) * PLANE + (size_t)s * PPB;
    const float* py = img + ((size_t)b * 3 + 1) * PLANE + (size_t)s * PPB;
    const float* pz = img + ((size_t)b * 3 + 2) * PLANE + (size_t)s * PPB;
    float*       po = out + ((size_t)bc)        * PLANE + (size_t)s * PPB;

    for (int base = threadIdx.x * 4; base < PPB; base += THREADS * 4) {
        const float4 xv = *reinterpret_cast<const float4*>(px + base);
        const float4 yv = *reinterpret_cast<const float4*>(py + base);
        const float4 zv = *reinterpret_cast<const float4*>(pz + base);
        float4 ov;

        #pragma unroll
        for (int k = 0; k < 4; ++k) {
            float x = (&xv.x)[k];
            float y = (&yv.x)[k];
            float z = (&zv.x)[k];

            float fx = fminf(fmaxf(x * 32.0f, 0.0f), 32.0f);
            float fy = fminf(fmaxf(y * 32.0f, 0.0f), 32.0f);
            float fz = fminf(fmaxf(z * 32.0f, 0.0f), 32.0f);

            float x0 = floorf(fx);
            float y0 = floorf(fy);
            float z0 = floorf(fz);

            int ix = (int)x0;
            int iy = (int)y0;
            int iz = (int)z0;

            float wx = fx - x0;
            float wy = fy - y0;
            float wz = fz - z0;

            int h  = (iz * NPTS + iy) * NPTS + ix;
            int dy = (iy < NPTS - 1) ? NPTS : 0;            // +33 unless y at border
            int dz = (iz < NPTS - 1) ? NPTS * NPTS : 0;     // +1089 unless z at border

            unsigned int p00 = slut[h];
            unsigned int p01 = slut[h + dy];
            unsigned int p10 = slut[h + dz];
            unsigned int p11 = slut[h + dy + dz];

            float2 a00 = __half22float2(*reinterpret_cast<__half2*>(&p00));
            float2 a01 = __half22float2(*reinterpret_cast<__half2*>(&p01));
            float2 a10 = __half22float2(*reinterpret_cast<__half2*>(&p10));
            float2 a11 = __half22float2(*reinterpret_cast<__half2*>(&p11));

            // x-lerp (pair second element is the x+1 corner; wx==0 at border)
            float v00 = a00.x + wx * (a00.y - a00.x);
            float v01 = a01.x + wx * (a01.y - a01.x);
            float v10 = a10.x + wx * (a10.y - a10.x);
            float v11 = a11.x + wx * (a11.y - a11.x);
            // y-lerp
            float v0 = v00 + wy * (v01 - v00);
            float v1 = v10 + wy * (v11 - v10);
            // z-lerp
            (&ov.x)[k] = v0 + wz * (v1 - v0);
        }

        *reinterpret_cast<float4*>(po + base) = ov;
    }
}

extern "C" void kernel_launch(void* const* d_in, const int* in_sizes, int n_in,
                              void* d_out, int out_size, void* d_ws, size_t ws_size,
                              hipStream_t stream) {
    const float* img = (const float*)d_in[0];
    const float* LUT = (const float*)d_in[1];
    float* out = (float*)d_out;

    dim3 grid(24 * SPLIT);
    dim3 block(THREADS);
    lut3d_kernel<<<grid, block, 0, stream>>>(img, LUT, out);
}

// Round 2
// 51.508 us; speedup vs baseline: 1.5554x; 1.5554x over previous
//
#include <hip/hip_runtime.h>
#include <hip/hip_fp16.h>

#define NPTS    33
#define NLUT    35937        // 33^3
#define PLANE   1048576      // 1024*1024
#define SPLIT   32           // blocks per (b,c) pair -> 24*32 = 768 = 3*256 CUs
#define PPB     (PLANE / SPLIT)   // 32768
#define THREADS 1024
#define UNROLL  8

__global__ __launch_bounds__(THREADS)
void lut3d_kernel(const float* __restrict__ img,
                  const float* __restrict__ LUT,
                  float* __restrict__ out)
{
    // packed half2 x-pairs: slut[h] = (LUT[h], LUT[h+1]) -> one b32 gather
    // yields both x-corners of a cell.
    __shared__ unsigned int slut[NLUT];

    const int blk = blockIdx.x;
    const int bc  = blk / SPLIT;      // 0..23  (b*3 + c)
    const int s   = blk % SPLIT;
    const int b   = bc / 3;

    // ---- stage LUT[b][c] into LDS as packed fp16 x-pairs (vectorized) ----
    const float* lutg = LUT + (size_t)bc * NLUT;
    for (int h = threadIdx.x * 4; h < NLUT - 1; h += THREADS * 4) {
        float4 v = *reinterpret_cast<const float4*>(lutg + h);
        float v4 = lutg[h + 4];
        __half2 p0 = __floats2half2_rn(v.x, v.y);
        __half2 p1 = __floats2half2_rn(v.y, v.z);
        __half2 p2 = __floats2half2_rn(v.z, v.w);
        __half2 p3 = __floats2half2_rn(v.w, v4);
        slut[h + 0] = *reinterpret_cast<unsigned int*>(&p0);
        slut[h + 1] = *reinterpret_cast<unsigned int*>(&p1);
        slut[h + 2] = *reinterpret_cast<unsigned int*>(&p2);
        slut[h + 3] = *reinterpret_cast<unsigned int*>(&p3);
    }
    if (threadIdx.x == 0) {
        float v = lutg[NLUT - 1];
        __half2 p = __floats2half2_rn(v, v);
        slut[NLUT - 1] = *reinterpret_cast<unsigned int*>(&p);
    }
    __syncthreads();

    const float* px = img + ((size_t)b * 3 + 0) * PLANE + (size_t)s * PPB;
    const float* py = img + ((size_t)b * 3 + 1) * PLANE + (size_t)s * PPB;
    const float* pz = img + ((size_t)b * 3 + 2) * PLANE + (size_t)s * PPB;
    float*       po = out + ((size_t)bc)        * PLANE + (size_t)s * PPB;

    // PPB = 32768 = 4 * THREADS * UNROLL  -> exactly 4 iterations
    for (int base = threadIdx.x * UNROLL; base < PPB; base += THREADS * UNROLL) {
        float xs[UNROLL], ys[UNROLL], zs[UNROLL], ov[UNROLL];
        *reinterpret_cast<float4*>(&xs[0]) = *reinterpret_cast<const float4*>(px + base);
        *reinterpret_cast<float4*>(&xs[4]) = *reinterpret_cast<const float4*>(px + base + 4);
        *reinterpret_cast<float4*>(&ys[0]) = *reinterpret_cast<const float4*>(py + base);
        *reinterpret_cast<float4*>(&ys[4]) = *reinterpret_cast<const float4*>(py + base + 4);
        *reinterpret_cast<float4*>(&zs[0]) = *reinterpret_cast<const float4*>(pz + base);
        *reinterpret_cast<float4*>(&zs[4]) = *reinterpret_cast<const float4*>(pz + base + 4);

        int   hh[UNROLL];
        float wx[UNROLL], wy[UNROLL], wz[UNROLL];

        #pragma unroll
        for (int k = 0; k < UNROLL; ++k) {
            // borderless: lerp(c[31],c[32],1.0) == lerp(c[32],*,0.0), so
            // clamping the integer cell to 31 with weight fx-ix is exact.
            float fx = fminf(fmaxf(xs[k] * 32.0f, 0.0f), 32.0f);
            float fy = fminf(fmaxf(ys[k] * 32.0f, 0.0f), 32.0f);
            float fz = fminf(fmaxf(zs[k] * 32.0f, 0.0f), 32.0f);
            int ix = min((int)fx, 31);
            int iy = min((int)fy, 31);
            int iz = min((int)fz, 31);
            wx[k] = fx - (float)ix;
            wy[k] = fy - (float)iy;
            wz[k] = fz - (float)iz;
            hh[k] = (iz * NPTS + iy) * NPTS + ix;
        }

        unsigned int p00[UNROLL], p01[UNROLL], p10[UNROLL], p11[UNROLL];
        #pragma unroll
        for (int k = 0; k < UNROLL; ++k) {
            const unsigned int* sp = slut + hh[k];
            // offsets 0/33 and 1089/1122 -> two ds_read2_b32 per pixel
            p00[k] = sp[0];
            p01[k] = sp[NPTS];
            p10[k] = sp[NPTS * NPTS];
            p11[k] = sp[NPTS * NPTS + NPTS];
        }

        #pragma unroll
        for (int k = 0; k < UNROLL; ++k) {
            float2 a00 = __half22float2(*reinterpret_cast<__half2*>(&p00[k]));
            float2 a01 = __half22float2(*reinterpret_cast<__half2*>(&p01[k]));
            float2 a10 = __half22float2(*reinterpret_cast<__half2*>(&p10[k]));
            float2 a11 = __half22float2(*reinterpret_cast<__half2*>(&p11[k]));

            float v00 = fmaf(wx[k], a00.y - a00.x, a00.x);
            float v01 = fmaf(wx[k], a01.y - a01.x, a01.x);
            float v10 = fmaf(wx[k], a10.y - a10.x, a10.x);
            float v11 = fmaf(wx[k], a11.y - a11.x, a11.x);

            float v0 = fmaf(wy[k], v01 - v00, v00);
            float v1 = fmaf(wy[k], v11 - v10, v10);

            ov[k] = fmaf(wz[k], v1 - v0, v0);
        }

        *reinterpret_cast<float4*>(po + base)     = *reinterpret_cast<float4*>(&ov[0]);
        *reinterpret_cast<float4*>(po + base + 4) = *reinterpret_cast<float4*>(&ov[4]);
    }
}

extern "C" void kernel_launch(void* const* d_in, const int* in_sizes, int n_in,
                              void* d_out, int out_size, void* d_ws, size_t ws_size,
                              hipStream_t stream) {
    const float* img = (const float*)d_in[0];
    const float* LUT = (const float*)d_in[1];
    float* out = (float*)d_out;

    dim3 grid(24 * SPLIT);
    dim3 block(THREADS);
    lut3d_kernel<<<grid, block, 0, stream>>>(img, LUT, out);
}